// Round 1
// baseline (493.776 us; speedup 1.0000x reference)
//
#include <hip/hip_runtime.h>

#define NN 8192
#define DD 64
#define NL 3
#define TI 16
#define TJ 128

// Kernel A: per-row f1/f2 for all 3 layers.
//   Wh[i][d] = sum_k X[i][k]*Ws[l][d][k] + bWs[l][d]
//   f1[l][i] = Wh . a1[l] (+ ba[l] folded), f2[l][i] = Wh . a2[l]
__global__ __launch_bounds__(256) void mas_setup(const float* __restrict__ X,
                                                 const float* __restrict__ Ws,
                                                 const float* __restrict__ bWs,
                                                 const float* __restrict__ a1,
                                                 const float* __restrict__ a2,
                                                 const float* __restrict__ ba,
                                                 float* __restrict__ f1b,
                                                 float* __restrict__ f2g) {
    const int l = blockIdx.x >> 5;                  // 3 layer groups of 32 blocks
    const int i = ((blockIdx.x & 31) << 8) + threadIdx.x;

    float xr[DD];
    const float4* X4 = (const float4*)(X + (size_t)i * DD);
#pragma unroll
    for (int q = 0; q < DD / 4; ++q) {
        float4 v = X4[q];
        xr[4 * q + 0] = v.x; xr[4 * q + 1] = v.y;
        xr[4 * q + 2] = v.z; xr[4 * q + 3] = v.w;
    }

    const float* W   = Ws  + l * DD * DD;
    const float* a1l = a1  + l * DD;
    const float* a2l = a2  + l * DD;
    const float* bwl = bWs + l * DD;

    float f1 = 0.f, f2 = 0.f;
    for (int d = 0; d < DD; ++d) {
        float wh = bwl[d];
        const float* wr = W + d * DD;
#pragma unroll
        for (int k = 0; k < DD; ++k) wh = fmaf(xr[k], wr[k], wh);
        f1 = fmaf(wh, a1l[d], f1);
        f2 = fmaf(wh, a2l[d], f2);
    }
    f1b[l * NN + i] = f1 + ba[l];
    f2g[l * NN + i] = f2;
}

// Kernel B: per row-tile of TI=16 rows, loop over all j in tiles of TJ=128.
//  W-phase: 256 threads compute w[16][128] (each thread: 1 row x 8 js) -> LDS,
//           accumulating per-layer Z partials in registers.
//  F-phase: thread (rF group, dF col) accumulates 4 rows' weighted X sums.
__global__ __launch_bounds__(256) void mas_main(const float* __restrict__ X,
                                                const float* __restrict__ f1b,
                                                const float* __restrict__ f2g,
                                                float* __restrict__ out) {
    __shared__ float Xs[TJ][68];      // padded: bank-conflict-free column reads
    __shared__ float f2t[NL][TJ];
    __shared__ float wst[TI][132];    // padded, 16B-aligned rows
    __shared__ float zs[TI][4];

    const int tid = threadIdx.x;
    const int i0 = blockIdx.x * TI;

    // W-phase role
    const int iW = tid >> 4;          // 0..15 (row within tile)
    const int jW = (tid & 15) << 3;   // 0..120 (8 consecutive j)
    const float f1r0 = f1b[0 * NN + i0 + iW];
    const float f1r1 = f1b[1 * NN + i0 + iW];
    const float f1r2 = f1b[2 * NN + i0 + iW];
    float z0 = 0.f, z1 = 0.f, z2 = 0.f;

    // F-phase role
    const int dF = tid & 63;
    const int rF = (tid >> 6) << 2;   // rows rF..rF+3
    float acc0 = 0.f, acc1 = 0.f, acc2 = 0.f, acc3 = 0.f;

    const float4* X4 = (const float4*)X;

    // prefetch tile 0 into registers
    float4 xv[8];
    float f2v0 = 0.f, f2v1 = 0.f, f2v2 = 0.f;
#pragma unroll
    for (int q = 0; q < 8; ++q) xv[q] = X4[tid + 256 * q];
    if (tid < TJ) {
        f2v0 = f2g[0 * NN + tid];
        f2v1 = f2g[1 * NN + tid];
        f2v2 = f2g[2 * NN + tid];
    }

    for (int jt = 0; jt < NN / TJ; ++jt) {
        // commit staged tile to LDS
#pragma unroll
        for (int q = 0; q < 8; ++q) {
            int f4i = tid + 256 * q;
            int row = f4i >> 4, c4 = f4i & 15;
            *(float4*)&Xs[row][c4 << 2] = xv[q];
        }
        if (tid < TJ) {
            f2t[0][tid] = f2v0; f2t[1][tid] = f2v1; f2t[2][tid] = f2v2;
        }
        __syncthreads();

        // prefetch next tile (latency hides under W+F phases)
        if (jt + 1 < NN / TJ) {
            const int j0n = (jt + 1) * TJ;
#pragma unroll
            for (int q = 0; q < 8; ++q) xv[q] = X4[j0n * (DD / 4) + tid + 256 * q];
            if (tid < TJ) {
                f2v0 = f2g[0 * NN + j0n + tid];
                f2v1 = f2g[1 * NN + j0n + tid];
                f2v2 = f2g[2 * NN + j0n + tid];
            }
        }

        // ---- W phase: w[iW][jW..jW+7], Z partials ----
        {
            float4 fa0 = *(const float4*)&f2t[0][jW];
            float4 fb0 = *(const float4*)&f2t[0][jW + 4];
            float4 fa1 = *(const float4*)&f2t[1][jW];
            float4 fb1 = *(const float4*)&f2t[1][jW + 4];
            float4 fa2 = *(const float4*)&f2t[2][jW];
            float4 fb2 = *(const float4*)&f2t[2][jW + 4];
            float p0[8] = {fa0.x, fa0.y, fa0.z, fa0.w, fb0.x, fb0.y, fb0.z, fb0.w};
            float p1[8] = {fa1.x, fa1.y, fa1.z, fa1.w, fb1.x, fb1.y, fb1.z, fb1.w};
            float p2[8] = {fa2.x, fa2.y, fa2.z, fa2.w, fb2.x, fb2.y, fb2.z, fb2.w};
            float w[8];
#pragma unroll
            for (int e = 0; e < 8; ++e) {
                float c0 = f1r0 + p0[e]; c0 = fmaxf(c0, 0.2f * c0); float e0 = __expf(c0);
                float c1 = f1r1 + p1[e]; c1 = fmaxf(c1, 0.2f * c1); float e1 = __expf(c1);
                float c2 = f1r2 + p2[e]; c2 = fmaxf(c2, 0.2f * c2); float e2 = __expf(c2);
                z0 += e0; z1 += e1; z2 += e2;
                w[e] = e0 * e1 * e2;
            }
            *(float4*)&wst[iW][jW]     = make_float4(w[0], w[1], w[2], w[3]);
            *(float4*)&wst[iW][jW + 4] = make_float4(w[4], w[5], w[6], w[7]);
        }
        __syncthreads();

        // ---- F phase: acc[m] += sum_j w[rF+m][j] * X[j][dF] ----
#pragma unroll 4
        for (int jj = 0; jj < TJ; jj += 4) {
            float4 w0 = *(const float4*)&wst[rF + 0][jj];
            float4 w1 = *(const float4*)&wst[rF + 1][jj];
            float4 w2 = *(const float4*)&wst[rF + 2][jj];
            float4 w3 = *(const float4*)&wst[rF + 3][jj];
            float x0 = Xs[jj + 0][dF];
            float x1 = Xs[jj + 1][dF];
            float x2 = Xs[jj + 2][dF];
            float x3 = Xs[jj + 3][dF];
            acc0 = fmaf(w0.x, x0, fmaf(w0.y, x1, fmaf(w0.z, x2, fmaf(w0.w, x3, acc0))));
            acc1 = fmaf(w1.x, x0, fmaf(w1.y, x1, fmaf(w1.z, x2, fmaf(w1.w, x3, acc1))));
            acc2 = fmaf(w2.x, x0, fmaf(w2.y, x1, fmaf(w2.z, x2, fmaf(w2.w, x3, acc2))));
            acc3 = fmaf(w3.x, x0, fmaf(w3.y, x1, fmaf(w3.z, x2, fmaf(w3.w, x3, acc3))));
        }
        __syncthreads();
    }

    // reduce Z over the 16 lanes sharing a row (lanes iW*16..iW*16+15, same wave)
    z0 += __shfl_xor(z0, 1); z0 += __shfl_xor(z0, 2); z0 += __shfl_xor(z0, 4); z0 += __shfl_xor(z0, 8);
    z1 += __shfl_xor(z1, 1); z1 += __shfl_xor(z1, 2); z1 += __shfl_xor(z1, 4); z1 += __shfl_xor(z1, 8);
    z2 += __shfl_xor(z2, 1); z2 += __shfl_xor(z2, 2); z2 += __shfl_xor(z2, 4); z2 += __shfl_xor(z2, 8);
    if ((tid & 15) == 0) { zs[iW][0] = z0; zs[iW][1] = z1; zs[iW][2] = z2; }
    __syncthreads();

    {
        float inv0 = 1.f / (zs[rF + 0][0] * zs[rF + 0][1] * zs[rF + 0][2]);
        float inv1 = 1.f / (zs[rF + 1][0] * zs[rF + 1][1] * zs[rF + 1][2]);
        float inv2 = 1.f / (zs[rF + 2][0] * zs[rF + 2][1] * zs[rF + 2][2]);
        float inv3 = 1.f / (zs[rF + 3][0] * zs[rF + 3][1] * zs[rF + 3][2]);
        out[(size_t)(i0 + rF + 0) * DD + dF] = acc0 * inv0;
        out[(size_t)(i0 + rF + 1) * DD + dF] = acc1 * inv1;
        out[(size_t)(i0 + rF + 2) * DD + dF] = acc2 * inv2;
        out[(size_t)(i0 + rF + 3) * DD + dF] = acc3 * inv3;
    }
}

extern "C" void kernel_launch(void* const* d_in, const int* in_sizes, int n_in,
                              void* d_out, int out_size, void* d_ws, size_t ws_size,
                              hipStream_t stream) {
    const float* X   = (const float*)d_in[0];
    // d_in[1] = A : unused by the reference computation (shape only)
    const float* Ws  = (const float*)d_in[2];
    const float* bWs = (const float*)d_in[3];
    const float* a1  = (const float*)d_in[4];
    const float* a2  = (const float*)d_in[5];
    const float* ba  = (const float*)d_in[6];
    float* out = (float*)d_out;

    float* f1b = (float*)d_ws;            // [3][8192] (ba folded in)
    float* f2g = f1b + NL * NN;           // [3][8192]

    mas_setup<<<96, 256, 0, stream>>>(X, Ws, bWs, a1, a2, ba, f1b, f2g);
    mas_main<<<NN / TI, 256, 0, stream>>>(X, f1b, f2g, out);
}

// Round 2
// 239.413 us; speedup vs baseline: 2.0624x; 2.0624x over previous
//
#include <hip/hip_runtime.h>

#define NN 8192
#define DD 64
#define NL 3
#define LOG2E 1.4426950408889634f

// Kernel A: per-row f1/f2 for all 3 layers, pre-scaled by log2(e) so the
// main loop can use the hardware 2^x directly (lrelu is positively
// homogeneous: lrelu(x)*c == lrelu(x*c) for c>0).
//   f1s[l][i] = (Wh.a1[l] + ba[l]) * LOG2E
//   f2p[i][l] = (Wh.a2[l]) * LOG2E   (packed float4 per row, .w unused)
__global__ __launch_bounds__(256) void mas_setup(const float* __restrict__ X,
                                                 const float* __restrict__ Ws,
                                                 const float* __restrict__ bWs,
                                                 const float* __restrict__ a1,
                                                 const float* __restrict__ a2,
                                                 const float* __restrict__ ba,
                                                 float* __restrict__ f1s,
                                                 float* __restrict__ f2p) {
    const int l = blockIdx.x >> 5;                  // 3 layer groups of 32 blocks
    const int i = ((blockIdx.x & 31) << 8) + threadIdx.x;

    float xr[DD];
    const float4* X4 = (const float4*)(X + (size_t)i * DD);
#pragma unroll
    for (int q = 0; q < DD / 4; ++q) {
        float4 v = X4[q];
        xr[4 * q + 0] = v.x; xr[4 * q + 1] = v.y;
        xr[4 * q + 2] = v.z; xr[4 * q + 3] = v.w;
    }

    const float* W   = Ws  + l * DD * DD;
    const float* a1l = a1  + l * DD;
    const float* a2l = a2  + l * DD;
    const float* bwl = bWs + l * DD;

    float f1 = 0.f, f2 = 0.f;
    for (int d = 0; d < DD; ++d) {
        float wh = bwl[d];
        const float* wr = W + d * DD;
#pragma unroll
        for (int k = 0; k < DD; ++k) wh = fmaf(xr[k], wr[k], wh);
        f1 = fmaf(wh, a1l[d], f1);
        f2 = fmaf(wh, a2l[d], f2);
    }
    f1s[l * NN + i] = (f1 + ba[l]) * LOG2E;
    f2p[i * 4 + l]  = f2 * LOG2E;           // component write, no race
}

// Kernel B: lane = row. Each wave handles 64 rows x (NN/nq/4) columns.
// w_ij generated per-lane in registers (no LDS), X rows reach the FMAs as
// wave-uniform scalar (SGPR) operands. acc[64] = per-lane output row partial.
__global__ __launch_bounds__(256, 2) void mas_main(const float* __restrict__ X,
                                                   const float* __restrict__ f1s,
                                                   const float* __restrict__ f2p4,
                                                   float* __restrict__ numws,
                                                   float* __restrict__ zws,
                                                   float* __restrict__ out,
                                                   int nq) {
    __shared__ float red[4][64][68];     // 69.6 KB: 4 wave partial tiles
    __shared__ float redz[4][3][64];

    const int lane = threadIdx.x & 63;
    const int wv   = __builtin_amdgcn_readfirstlane(threadIdx.x >> 6); // wave id, SGPR
    const int rt   = blockIdx.x;          // row tile (64 rows)
    const int q    = blockIdx.y;          // j-split index
    const int i    = rt * 64 + lane;
    const int jspan = NN / nq;
    const int wspan = jspan / 4;
    const int jbase = q * jspan + wv * wspan;

    const float f10 = f1s[0 * NN + i];
    const float f11 = f1s[1 * NN + i];
    const float f12 = f1s[2 * NN + i];

    float acc[DD];
#pragma unroll
    for (int d = 0; d < DD; ++d) acc[d] = 0.f;
    float z0 = 0.f, z1 = 0.f, z2 = 0.f;

    const float4* f2p = (const float4*)f2p4;

    for (int jj = 0; jj < wspan; ++jj) {
        const int j = jbase + jj;                 // wave-uniform
        const float4 f2 = f2p[j];                 // s_load_dwordx4
        const float4* xr = (const float4*)(X + (size_t)j * DD);
        float4 xv[16];                            // wave-uniform -> SGPRs
#pragma unroll
        for (int t = 0; t < 16; ++t) xv[t] = xr[t];

        float c0 = f10 + f2.x; c0 = fmaxf(c0, 0.2f * c0); const float e0 = exp2f(c0);
        float c1 = f11 + f2.y; c1 = fmaxf(c1, 0.2f * c1); const float e1 = exp2f(c1);
        float c2 = f12 + f2.z; c2 = fmaxf(c2, 0.2f * c2); const float e2 = exp2f(c2);
        z0 += e0; z1 += e1; z2 += e2;
        const float w = e0 * (e1 * e2);

#pragma unroll
        for (int t = 0; t < 16; ++t) {
            acc[4 * t + 0] = fmaf(w, xv[t].x, acc[4 * t + 0]);
            acc[4 * t + 1] = fmaf(w, xv[t].y, acc[4 * t + 1]);
            acc[4 * t + 2] = fmaf(w, xv[t].z, acc[4 * t + 2]);
            acc[4 * t + 3] = fmaf(w, xv[t].w, acc[4 * t + 3]);
        }
    }

    // stash all 4 waves' partial tiles + Z partials
#pragma unroll
    for (int t = 0; t < 16; ++t)
        *(float4*)&red[wv][lane][4 * t] =
            make_float4(acc[4 * t], acc[4 * t + 1], acc[4 * t + 2], acc[4 * t + 3]);
    redz[wv][0][lane] = z0;
    redz[wv][1][lane] = z1;
    redz[wv][2][lane] = z2;
    __syncthreads();

    // 256 threads reduce & store: thread -> (row r = tid>>2, 16-col chunk)
    {
        const int r  = threadIdx.x >> 2;
        const int db = (threadIdx.x & 3) << 4;
        float s[16];
#pragma unroll
        for (int u = 0; u < 16; ++u) s[u] = 0.f;
#pragma unroll
        for (int wy = 0; wy < 4; ++wy) {
#pragma unroll
            for (int u = 0; u < 4; ++u) {
                float4 v = *(const float4*)&red[wy][r][db + 4 * u];
                s[4 * u + 0] += v.x; s[4 * u + 1] += v.y;
                s[4 * u + 2] += v.z; s[4 * u + 3] += v.w;
            }
        }
        const size_t orow = (size_t)(rt * 64 + r) * DD + db;
        if (nq == 1) {
            const float Z0 = redz[0][0][r] + redz[1][0][r] + redz[2][0][r] + redz[3][0][r];
            const float Z1 = redz[0][1][r] + redz[1][1][r] + redz[2][1][r] + redz[3][1][r];
            const float Z2 = redz[0][2][r] + redz[1][2][r] + redz[2][2][r] + redz[3][2][r];
            const float inv = 1.f / (Z0 * (Z1 * Z2));
#pragma unroll
            for (int u = 0; u < 4; ++u)
                *(float4*)&out[orow + 4 * u] = make_float4(s[4*u] * inv, s[4*u+1] * inv,
                                                           s[4*u+2] * inv, s[4*u+3] * inv);
        } else {
            float* np = numws + (size_t)q * NN * DD + orow;
#pragma unroll
            for (int u = 0; u < 4; ++u)
                *(float4*)&np[4 * u] = make_float4(s[4*u], s[4*u+1], s[4*u+2], s[4*u+3]);
            if ((threadIdx.x & 3) == 0) {
                const int row = rt * 64 + r;
                const float Z0 = redz[0][0][r] + redz[1][0][r] + redz[2][0][r] + redz[3][0][r];
                const float Z1 = redz[0][1][r] + redz[1][1][r] + redz[2][1][r] + redz[3][1][r];
                const float Z2 = redz[0][2][r] + redz[1][2][r] + redz[2][2][r] + redz[3][2][r];
                zws[(q * 3 + 0) * NN + row] = Z0;
                zws[(q * 3 + 1) * NN + row] = Z1;
                zws[(q * 3 + 2) * NN + row] = Z2;
            }
        }
    }
}

// Kernel C: combine j-split partials (fixed-order fp32, deterministic).
__global__ __launch_bounds__(256) void mas_combine(const float* __restrict__ numws,
                                                   const float* __restrict__ zws,
                                                   float* __restrict__ out, int nq) {
    const int idx = blockIdx.x * 256 + threadIdx.x;   // over NN*DD
    const int i = idx >> 6;
    float s = 0.f;
    for (int q = 0; q < nq; ++q) s += numws[(size_t)q * NN * DD + idx];
    float Z0 = 0.f, Z1 = 0.f, Z2 = 0.f;
    for (int q = 0; q < nq; ++q) {
        Z0 += zws[(q * 3 + 0) * NN + i];
        Z1 += zws[(q * 3 + 1) * NN + i];
        Z2 += zws[(q * 3 + 2) * NN + i];
    }
    out[idx] = s / (Z0 * (Z1 * Z2));
}

extern "C" void kernel_launch(void* const* d_in, const int* in_sizes, int n_in,
                              void* d_out, int out_size, void* d_ws, size_t ws_size,
                              hipStream_t stream) {
    const float* X   = (const float*)d_in[0];
    // d_in[1] = A : unused by the reference computation (shape only)
    const float* Ws  = (const float*)d_in[2];
    const float* bWs = (const float*)d_in[3];
    const float* a1  = (const float*)d_in[4];
    const float* a2  = (const float*)d_in[5];
    const float* ba  = (const float*)d_in[6];
    float* out = (float*)d_out;

    float* f1s   = (float*)d_ws;                 // [3][NN]
    float* f2p   = f1s + NL * NN;                // [NN][4]
    float* numws = f2p + 4 * NN;                 // [nq][NN][DD]
    const size_t fixed = (size_t)(NL * NN + 4 * NN) * 4;
    const size_t per_q = ((size_t)NN * DD + 3 * NN) * 4;
    const int nq = (ws_size >= fixed + 4 * per_q) ? 4 : 1;
    float* zws = numws + (size_t)nq * NN * DD;   // [nq][3][NN]

    mas_setup<<<96, 256, 0, stream>>>(X, Ws, bWs, a1, a2, ba, f1s, f2p);
    dim3 grid(NN / 64, nq);
    mas_main<<<grid, 256, 0, stream>>>(X, f1s, f2p, numws, zws, out, nq);
    if (nq > 1)
        mas_combine<<<NN * DD / 256, 256, 0, stream>>>(numws, zws, out, nq);
}

// Round 3
// 105.079 us; speedup vs baseline: 4.6991x; 2.2784x over previous
//
#include <hip/hip_runtime.h>

#define NN 8192
#define DD 64
#define NL 3
#define LOG2E 1.4426950408889634f
#define WSCALE 0.000244140625f    // 2^-12
#define WUNSCALE 4096.0f

typedef _Float16 f16x8 __attribute__((ext_vector_type(8)));
typedef float f32x16 __attribute__((ext_vector_type(16)));

// Kernel A: per-row f1/f2 for all 3 layers, pre-scaled by log2(e).
__global__ __launch_bounds__(256) void mas_setup(const float* __restrict__ X,
                                                 const float* __restrict__ Ws,
                                                 const float* __restrict__ bWs,
                                                 const float* __restrict__ a1,
                                                 const float* __restrict__ a2,
                                                 const float* __restrict__ ba,
                                                 float* __restrict__ f1s,
                                                 float* __restrict__ f2T) {
    const int l = blockIdx.x >> 5;
    const int i = ((blockIdx.x & 31) << 8) + threadIdx.x;

    float xr[DD];
    const float4* X4 = (const float4*)(X + (size_t)i * DD);
#pragma unroll
    for (int q = 0; q < DD / 4; ++q) {
        float4 v = X4[q];
        xr[4 * q + 0] = v.x; xr[4 * q + 1] = v.y;
        xr[4 * q + 2] = v.z; xr[4 * q + 3] = v.w;
    }

    const float* W   = Ws  + l * DD * DD;
    const float* a1l = a1  + l * DD;
    const float* a2l = a2  + l * DD;
    const float* bwl = bWs + l * DD;

    float f1 = 0.f, f2 = 0.f;
    for (int d = 0; d < DD; ++d) {
        float wh = bwl[d];
        const float* wr = W + d * DD;
#pragma unroll
        for (int k = 0; k < DD; ++k) wh = fmaf(xr[k], wr[k], wh);
        f1 = fmaf(wh, a1l[d], f1);
        f2 = fmaf(wh, a2l[d], f2);
    }
    f1s[l * NN + i] = (f1 + ba[l]) * LOG2E;
    f2T[l * NN + i] = f2 * LOG2E;
}

// Kernel B: X (fp32 row-major) -> fp16 in exact 32x32x16 B-fragment order.
// Fragment element (S, tile, lane, e) holds X[S*16 + (lane>>5)*8 + e][tile*32 + (lane&31)].
// Flat f16x8 index = (S*2 + tile)*64 + lane.
__global__ __launch_bounds__(256) void mas_xfrag(const float* __restrict__ X,
                                                 _Float16* __restrict__ Xf) {
    const int t = blockIdx.x * 256 + threadIdx.x;   // 0..65535
    const int lane = t & 63;
    const int st = t >> 6;                           // S*2 + tile
    const int S = st >> 1, tl = st & 1;
    const int d = tl * 32 + (lane & 31);
    const int j0 = S * 16 + (lane >> 5) * 8;
    f16x8 v;
#pragma unroll
    for (int e = 0; e < 8; ++e) v[e] = (_Float16)X[(size_t)(j0 + e) * DD + d];
    *(f16x8*)(Xf + (size_t)t * 8) = v;
}

// Kernel C: main. Wave = 32-row tile x its j-span. A-frag (w) generated in
// registers; B-frag = one coalesced 16B load per tile. No LDS in main loop.
__global__ __launch_bounds__(256, 4) void mas_main3(const _Float16* __restrict__ Xf,
                                                    const float* __restrict__ f1s,
                                                    const float* __restrict__ f2T,
                                                    float* __restrict__ numpart,
                                                    float* __restrict__ zpart,
                                                    float* __restrict__ out,
                                                    int nqb) {
    __shared__ float red[4][64][33];    // [wave][col d][row] epilogue reduce
    __shared__ float zred[4][3][32];
    __shared__ float zfin[3][32];

    const int tid  = threadIdx.x;
    const int lane = tid & 63;
    const int wv   = tid >> 6;
    const int hi   = lane >> 5;
    const int row  = lane & 31;
    const int rt   = blockIdx.x;        // 0..255 row tiles
    const int q    = blockIdx.y;        // j-split
    const int i    = rt * 32 + row;

    const float f10 = f1s[0 * NN + i];
    const float f11 = f1s[1 * NN + i];
    const float f12 = f1s[2 * NN + i];

    const int jspan = NN / nqb;         // per block
    const int wspan = jspan >> 2;       // per wave
    const int jbase = q * jspan + wv * wspan;
    const int s0    = jbase >> 4;       // first global k-step
    const int nst   = wspan >> 4;

    const float* p20 = f2T + 0 * NN + jbase + hi * 8;
    const float* p21 = f2T + 1 * NN + jbase + hi * 8;
    const float* p22 = f2T + 2 * NN + jbase + hi * 8;
    const f16x8* pB  = (const f16x8*)Xf + (size_t)s0 * 128 + lane;

    f32x16 acc0 = {};
    f32x16 acc1 = {};
    float z0 = 0.f, z1 = 0.f, z2 = 0.f;

    for (int s = 0; s < nst; ++s) {
        const float4 a0 = *(const float4*)(p20 + s * 16);
        const float4 b0 = *(const float4*)(p20 + s * 16 + 4);
        const float4 a1v = *(const float4*)(p21 + s * 16);
        const float4 b1v = *(const float4*)(p21 + s * 16 + 4);
        const float4 a2v = *(const float4*)(p22 + s * 16);
        const float4 b2v = *(const float4*)(p22 + s * 16 + 4);
        const f16x8 vb0 = pB[s * 128];
        const f16x8 vb1 = pB[s * 128 + 64];

        const float f20[8] = {a0.x, a0.y, a0.z, a0.w, b0.x, b0.y, b0.z, b0.w};
        const float f21[8] = {a1v.x, a1v.y, a1v.z, a1v.w, b1v.x, b1v.y, b1v.z, b1v.w};
        const float f22[8] = {a2v.x, a2v.y, a2v.z, a2v.w, b2v.x, b2v.y, b2v.z, b2v.w};

        f16x8 va;
#pragma unroll
        for (int e = 0; e < 8; ++e) {
            float c0 = f10 + f20[e]; c0 = fmaxf(c0, 0.2f * c0); const float e0 = exp2f(c0);
            float c1 = f11 + f21[e]; c1 = fmaxf(c1, 0.2f * c1); const float e1 = exp2f(c1);
            float c2 = f12 + f22[e]; c2 = fmaxf(c2, 0.2f * c2); const float e2 = exp2f(c2);
            z0 += e0; z1 += e1; z2 += e2;
            const float w = fminf(e0 * e1 * (e2 * WSCALE), 60000.0f);
            va[e] = (_Float16)w;
        }
        acc0 = __builtin_amdgcn_mfma_f32_32x32x16_f16(va, vb0, acc0, 0, 0, 0);
        acc1 = __builtin_amdgcn_mfma_f32_32x32x16_f16(va, vb1, acc1, 0, 0, 0);
    }

    // z: lanes (l, l+32) hold same row, disjoint k-groups
    z0 += __shfl_xor(z0, 32);
    z1 += __shfl_xor(z1, 32);
    z2 += __shfl_xor(z2, 32);

    // C frags -> LDS: C row = (reg&3) + 8*(reg>>2) + 4*hi, col = lane&31 (+32)
#pragma unroll
    for (int g = 0; g < 4; ++g) {
        const int rb = 8 * g + 4 * hi;
        *(float4*)&red[wv][row][rb] =
            make_float4(acc0[4 * g], acc0[4 * g + 1], acc0[4 * g + 2], acc0[4 * g + 3]);
        *(float4*)&red[wv][row + 32][rb] =
            make_float4(acc1[4 * g], acc1[4 * g + 1], acc1[4 * g + 2], acc1[4 * g + 3]);
    }
    if (lane < 32) {
        zred[wv][0][row] = z0; zred[wv][1][row] = z1; zred[wv][2][row] = z2;
    }
    __syncthreads();

    if (tid < 96) {
        const int l = tid >> 5, r = tid & 31;
        const float Z = zred[0][l][r] + zred[1][l][r] + zred[2][l][r] + zred[3][l][r];
        if (nqb > 1) zpart[((size_t)q * 3 + l) * NN + rt * 32 + r] = Z;
        else zfin[l][r] = Z;
    }
    __syncthreads();

    // cross-wave sum: thread -> (col = tid&63, rows r0..r0+7)
    {
        const int col = tid & 63;
        const int r0 = (tid >> 6) * 8;
        float s[8] = {0, 0, 0, 0, 0, 0, 0, 0};
#pragma unroll
        for (int w = 0; w < 4; ++w) {
            const float4 u = *(const float4*)&red[w][col][r0];
            const float4 v = *(const float4*)&red[w][col][r0 + 4];
            s[0] += u.x; s[1] += u.y; s[2] += u.z; s[3] += u.w;
            s[4] += v.x; s[5] += v.y; s[6] += v.z; s[7] += v.w;
        }
        if (nqb > 1) {
            float* np = numpart + ((size_t)q * NN + (size_t)rt * 32) * DD;
#pragma unroll
            for (int u = 0; u < 8; ++u) np[(size_t)(r0 + u) * DD + col] = s[u];
        } else {
#pragma unroll
            for (int u = 0; u < 8; ++u) {
                const int r = r0 + u;
                const float inv = WUNSCALE / (zfin[0][r] * (zfin[1][r] * zfin[2][r]));
                out[(size_t)(rt * 32 + r) * DD + col] = s[u] * inv;
            }
        }
    }
}

// Kernel D: combine j-split partials (fixed order, deterministic).
__global__ __launch_bounds__(256) void mas_comb3(const float* __restrict__ numpart,
                                                 const float* __restrict__ zpart,
                                                 float* __restrict__ out, int nqb) {
    const int idx = blockIdx.x * 256 + threadIdx.x;   // over NN*DD
    const int i = idx >> 6;
    float s = 0.f;
    for (int q = 0; q < nqb; ++q) s += numpart[(size_t)q * NN * DD + idx];
    float Z0 = 0.f, Z1 = 0.f, Z2 = 0.f;
    for (int q = 0; q < nqb; ++q) {
        Z0 += zpart[((size_t)q * 3 + 0) * NN + i];
        Z1 += zpart[((size_t)q * 3 + 1) * NN + i];
        Z2 += zpart[((size_t)q * 3 + 2) * NN + i];
    }
    out[idx] = s * WUNSCALE / (Z0 * (Z1 * Z2));
}

extern "C" void kernel_launch(void* const* d_in, const int* in_sizes, int n_in,
                              void* d_out, int out_size, void* d_ws, size_t ws_size,
                              hipStream_t stream) {
    const float* X   = (const float*)d_in[0];
    // d_in[1] = A : unused by the reference computation (shape only)
    const float* Ws  = (const float*)d_in[2];
    const float* bWs = (const float*)d_in[3];
    const float* a1  = (const float*)d_in[4];
    const float* a2  = (const float*)d_in[5];
    const float* ba  = (const float*)d_in[6];
    float* out = (float*)d_out;

    float* f1s = (float*)d_ws;                       // [3][NN] f32
    float* f2T = f1s + NL * NN;                      // [3][NN] f32
    _Float16* Xf = (_Float16*)(f2T + NL * NN);       // [NN*DD] f16 fragment order

    const size_t fixed = (size_t)(2 * NL * NN) * 4 + (size_t)NN * DD * 2;
    const size_t per_q = (size_t)NN * DD * 4 + (size_t)NL * NN * 4;
    int nqb = 1;
    if (ws_size >= fixed + 4 * per_q) nqb = 4;
    else if (ws_size >= fixed + 2 * per_q) nqb = 2;

    float* numpart = (float*)(Xf + (size_t)NN * DD); // [nqb][NN][DD] f32
    float* zpart   = numpart + (size_t)nqb * NN * DD; // [nqb][3][NN] f32

    mas_setup<<<96, 256, 0, stream>>>(X, Ws, bWs, a1, a2, ba, f1s, f2T);
    mas_xfrag<<<256, 256, 0, stream>>>(X, Xf);
    dim3 grid(NN / 32, nqb);
    mas_main3<<<grid, 256, 0, stream>>>(Xf, f1s, f2T, numpart, zpart, out, nqb);
    if (nqb > 1)
        mas_comb3<<<NN * DD / 256, 256, 0, stream>>>(numpart, zpart, out, nqb);
}

// Round 5
// 88.625 us; speedup vs baseline: 5.5715x; 1.1857x over previous
//
#include <hip/hip_runtime.h>

#define NN 8192
#define DD 64
#define NL 3
#define LOG2E 1.4426950408889634f

typedef _Float16 f16x8 __attribute__((ext_vector_type(8)));
typedef __fp16 fp16x2 __attribute__((ext_vector_type(2)));
typedef float f32x16 __attribute__((ext_vector_type(16)));

// Fused prep kernel.
// Blocks [0,96): per-row f1/f2 for 3 layers -> exp-domain tables:
//   a = (f1+ba)*log2e, b = f2*log2e
//   T[l][i]  = 2^(-a)         (sign-test threshold: c>0  <=>  E2 > T)
//   E1[l][i] = 2^a * 2^-4     (2^-4 fp16-range scale; cancels against Z)
//   E1s[l][i]= 2^(0.2a) * 2^-4
//   E2[l][j] = 2^b,  E2s[l][j] = 2^(0.2b)
// Blocks [96,352): X (f32 row-major) -> fp16 in 32x32x16 B-fragment order.
__global__ __launch_bounds__(256) void mas_prep(const float* __restrict__ X,
                                                const float* __restrict__ Ws,
                                                const float* __restrict__ bWs,
                                                const float* __restrict__ a1,
                                                const float* __restrict__ a2,
                                                const float* __restrict__ ba,
                                                float* __restrict__ T,
                                                float* __restrict__ E1,
                                                float* __restrict__ E1s,
                                                float* __restrict__ E2,
                                                float* __restrict__ E2s,
                                                _Float16* __restrict__ Xf) {
    if (blockIdx.x < 96) {
        const int l = blockIdx.x >> 5;
        const int i = ((blockIdx.x & 31) << 8) + threadIdx.x;

        float xr[DD];
        const float4* X4 = (const float4*)(X + (size_t)i * DD);
#pragma unroll
        for (int q = 0; q < DD / 4; ++q) {
            float4 v = X4[q];
            xr[4 * q + 0] = v.x; xr[4 * q + 1] = v.y;
            xr[4 * q + 2] = v.z; xr[4 * q + 3] = v.w;
        }

        const float* W   = Ws  + l * DD * DD;
        const float* a1l = a1  + l * DD;
        const float* a2l = a2  + l * DD;
        const float* bwl = bWs + l * DD;

        float f1 = 0.f, f2 = 0.f;
#pragma unroll 2
        for (int d = 0; d < DD; ++d) {
            float wh = bwl[d];
            const float* wr = W + d * DD;
#pragma unroll
            for (int k = 0; k < DD; ++k) wh = fmaf(xr[k], wr[k], wh);
            f1 = fmaf(wh, a1l[d], f1);
            f2 = fmaf(wh, a2l[d], f2);
        }
        const float a = (f1 + ba[l]) * LOG2E;
        const float b = f2 * LOG2E;
        T  [l * NN + i] = exp2f(-a);
        E1 [l * NN + i] = exp2f(a) * 0.0625f;
        E1s[l * NN + i] = exp2f(0.2f * a) * 0.0625f;
        E2 [l * NN + i] = exp2f(b);
        E2s[l * NN + i] = exp2f(0.2f * b);
    } else {
        // X -> fp16 B-fragment order. Element (S,tile,lane,e) holds
        // X[S*16 + (lane>>5)*8 + e][tile*32 + (lane&31)]; flat = (S*2+tile)*64+lane.
        const int t = (blockIdx.x - 96) * 256 + threadIdx.x;   // 0..65535
        const int lane = t & 63;
        const int st = t >> 6;
        const int S = st >> 1, tl = st & 1;
        const int d = tl * 32 + (lane & 31);
        const int j0 = S * 16 + (lane >> 5) * 8;
        f16x8 v;
#pragma unroll
        for (int e = 0; e < 8; ++e) v[e] = (_Float16)X[(size_t)(j0 + e) * DD + d];
        *(f16x8*)(Xf + (size_t)t * 8) = v;
    }
}

// Main: wave = 32-row tile x j-span. No transcendentals, no LDS in the loop.
// e_l = (E2>T ? E2 : E2s) * (E2>T ? E1 : E1s); w = e0*e1*e2 (2^-12-scaled,
// scale cancels against identically-scaled Z in the finalize).
__global__ __launch_bounds__(256, 4) void mas_main4(const _Float16* __restrict__ Xf,
                                                    const float* __restrict__ T,
                                                    const float* __restrict__ E1,
                                                    const float* __restrict__ E1s,
                                                    const float* __restrict__ E2,
                                                    const float* __restrict__ E2s,
                                                    float* __restrict__ numpart,
                                                    float* __restrict__ zpart,
                                                    float* __restrict__ out,
                                                    int nqb) {
    __shared__ float red[4][64][33];
    __shared__ float zred[4][3][32];
    __shared__ float zfin[3][32];

    const int tid  = threadIdx.x;
    const int lane = tid & 63;
    const int wv   = tid >> 6;
    const int hi   = lane >> 5;
    const int row  = lane & 31;
    const int rt   = blockIdx.x;
    const int q    = blockIdx.y;
    const int i    = rt * 32 + row;

    const float T0 = T[0 * NN + i], T1 = T[1 * NN + i], T2 = T[2 * NN + i];
    const float E10 = E1[0 * NN + i], E11 = E1[1 * NN + i], E12 = E1[2 * NN + i];
    const float F10 = E1s[0 * NN + i], F11 = E1s[1 * NN + i], F12 = E1s[2 * NN + i];

    const int jspan = NN / nqb;
    const int wspan = jspan >> 2;
    const int jbase = q * jspan + wv * wspan;
    const int s0    = jbase >> 4;
    const int nst   = wspan >> 4;

    const float* q20  = E2  + 0 * NN + jbase + hi * 8;
    const float* q2s0 = E2s + 0 * NN + jbase + hi * 8;
    const float* q21  = E2  + 1 * NN + jbase + hi * 8;
    const float* q2s1 = E2s + 1 * NN + jbase + hi * 8;
    const float* q22  = E2  + 2 * NN + jbase + hi * 8;
    const float* q2s2 = E2s + 2 * NN + jbase + hi * 8;
    const f16x8* pB   = (const f16x8*)Xf + (size_t)s0 * 128 + lane;

    f32x16 acc0 = {};
    f32x16 acc1 = {};
    float z0 = 0.f, z1 = 0.f, z2 = 0.f;

    for (int s = 0; s < nst; ++s) {
        const int o = s * 16;
        const f16x8 vb0 = pB[s * 128];
        const f16x8 vb1 = pB[s * 128 + 64];
        const float4 A0 = *(const float4*)(q20 + o);
        const float4 B0 = *(const float4*)(q20 + o + 4);
        const float4 C0 = *(const float4*)(q2s0 + o);
        const float4 D0 = *(const float4*)(q2s0 + o + 4);
        const float4 A1 = *(const float4*)(q21 + o);
        const float4 B1 = *(const float4*)(q21 + o + 4);
        const float4 C1 = *(const float4*)(q2s1 + o);
        const float4 D1 = *(const float4*)(q2s1 + o + 4);
        const float4 A2 = *(const float4*)(q22 + o);
        const float4 B2 = *(const float4*)(q22 + o + 4);
        const float4 C2 = *(const float4*)(q2s2 + o);
        const float4 D2 = *(const float4*)(q2s2 + o + 4);

        const float g0[8] = {A0.x, A0.y, A0.z, A0.w, B0.x, B0.y, B0.z, B0.w};
        const float h0[8] = {C0.x, C0.y, C0.z, C0.w, D0.x, D0.y, D0.z, D0.w};
        const float g1[8] = {A1.x, A1.y, A1.z, A1.w, B1.x, B1.y, B1.z, B1.w};
        const float h1[8] = {C1.x, C1.y, C1.z, C1.w, D1.x, D1.y, D1.z, D1.w};
        const float g2[8] = {A2.x, A2.y, A2.z, A2.w, B2.x, B2.y, B2.z, B2.w};
        const float h2[8] = {C2.x, C2.y, C2.z, C2.w, D2.x, D2.y, D2.z, D2.w};

        float w[8];
#pragma unroll
        for (int e = 0; e < 8; ++e) {
            const bool c0 = g0[e] > T0;
            const bool c1 = g1[e] > T1;
            const bool c2 = g2[e] > T2;
            const float e0 = (c0 ? g0[e] : h0[e]) * (c0 ? E10 : F10);
            const float e1 = (c1 ? g1[e] : h1[e]) * (c1 ? E11 : F11);
            const float e2 = (c2 ? g2[e] : h2[e]) * (c2 ? E12 : F12);
            z0 += e0; z1 += e1; z2 += e2;
            w[e] = fminf(e0 * (e1 * e2), 60000.0f);
        }
        union { f16x8 v8; fp16x2 h2v[4]; } u;
#pragma unroll
        for (int e = 0; e < 4; ++e)
            u.h2v[e] = __builtin_amdgcn_cvt_pkrtz(w[2 * e], w[2 * e + 1]);

        acc0 = __builtin_amdgcn_mfma_f32_32x32x16_f16(u.v8, vb0, acc0, 0, 0, 0);
        acc1 = __builtin_amdgcn_mfma_f32_32x32x16_f16(u.v8, vb1, acc1, 0, 0, 0);
    }

    // lanes (l, l+32) hold same row, disjoint j-halves
    z0 += __shfl_xor(z0, 32);
    z1 += __shfl_xor(z1, 32);
    z2 += __shfl_xor(z2, 32);

    // C frags -> LDS: C row = (reg&3) + 8*(reg>>2) + 4*hi, col = lane&31 (+32)
#pragma unroll
    for (int g = 0; g < 4; ++g) {
        const int rb = 8 * g + 4 * hi;
        *(float4*)&red[wv][row][rb] =
            make_float4(acc0[4 * g], acc0[4 * g + 1], acc0[4 * g + 2], acc0[4 * g + 3]);
        *(float4*)&red[wv][row + 32][rb] =
            make_float4(acc1[4 * g], acc1[4 * g + 1], acc1[4 * g + 2], acc1[4 * g + 3]);
    }
    if (lane < 32) {
        zred[wv][0][row] = z0; zred[wv][1][row] = z1; zred[wv][2][row] = z2;
    }
    __syncthreads();

    if (tid < 96) {
        const int l = tid >> 5, r = tid & 31;
        const float Z = zred[0][l][r] + zred[1][l][r] + zred[2][l][r] + zred[3][l][r];
        if (nqb > 1) zpart[((size_t)q * 3 + l) * NN + rt * 32 + r] = Z;
        else zfin[l][r] = Z;
    }
    __syncthreads();

    {
        const int col = tid & 63;
        const int r0 = (tid >> 6) * 8;
        float s[8] = {0, 0, 0, 0, 0, 0, 0, 0};
#pragma unroll
        for (int w = 0; w < 4; ++w) {
            const float4 u = *(const float4*)&red[w][col][r0];
            const float4 v = *(const float4*)&red[w][col][r0 + 4];
            s[0] += u.x; s[1] += u.y; s[2] += u.z; s[3] += u.w;
            s[4] += v.x; s[5] += v.y; s[6] += v.z; s[7] += v.w;
        }
        if (nqb > 1) {
            float* np = numpart + ((size_t)q * NN + (size_t)rt * 32) * DD;
#pragma unroll
            for (int u2 = 0; u2 < 8; ++u2) np[(size_t)(r0 + u2) * DD + col] = s[u2];
        } else {
#pragma unroll
            for (int u2 = 0; u2 < 8; ++u2) {
                const int r = r0 + u2;
                const float inv = 1.0f / (zfin[0][r] * (zfin[1][r] * zfin[2][r]));
                out[(size_t)(rt * 32 + r) * DD + col] = s[u2] * inv;
            }
        }
    }
}

// Combine j-split partials (fixed order, deterministic). Scales cancel.
__global__ __launch_bounds__(256) void mas_comb4(const float* __restrict__ numpart,
                                                 const float* __restrict__ zpart,
                                                 float* __restrict__ out, int nqb) {
    const int idx = blockIdx.x * 256 + threadIdx.x;
    const int i = idx >> 6;
    float s = 0.f;
    for (int q = 0; q < nqb; ++q) s += numpart[(size_t)q * NN * DD + idx];
    float Z0 = 0.f, Z1 = 0.f, Z2 = 0.f;
    for (int q = 0; q < nqb; ++q) {
        Z0 += zpart[((size_t)q * 3 + 0) * NN + i];
        Z1 += zpart[((size_t)q * 3 + 1) * NN + i];
        Z2 += zpart[((size_t)q * 3 + 2) * NN + i];
    }
    out[idx] = s / (Z0 * (Z1 * Z2));
}

extern "C" void kernel_launch(void* const* d_in, const int* in_sizes, int n_in,
                              void* d_out, int out_size, void* d_ws, size_t ws_size,
                              hipStream_t stream) {
    const float* X   = (const float*)d_in[0];
    // d_in[1] = A : unused by the reference computation (shape only)
    const float* Ws  = (const float*)d_in[2];
    const float* bWs = (const float*)d_in[3];
    const float* a1  = (const float*)d_in[4];
    const float* a2  = (const float*)d_in[5];
    const float* ba  = (const float*)d_in[6];
    float* out = (float*)d_out;

    float* Tt  = (float*)d_ws;                 // [3][NN]
    float* E1  = Tt  + NL * NN;                // [3][NN]
    float* E1s = E1  + NL * NN;                // [3][NN]
    float* E2  = E1s + NL * NN;                // [3][NN]
    float* E2s = E2  + NL * NN;                // [3][NN]
    _Float16* Xf = (_Float16*)(E2s + NL * NN); // [NN*DD] f16 fragment order

    const size_t fixed = (size_t)(5 * NL * NN) * 4 + (size_t)NN * DD * 2;
    const size_t per_q = (size_t)NN * DD * 4 + (size_t)NL * NN * 4;
    int nqb = 1;
    if (ws_size >= fixed + 4 * per_q) nqb = 4;
    else if (ws_size >= fixed + 2 * per_q) nqb = 2;

    float* numpart = (float*)(Xf + (size_t)NN * DD);  // [nqb][NN][DD]
    float* zpart   = numpart + (size_t)nqb * NN * DD; // [nqb][3][NN]

    mas_prep<<<352, 256, 0, stream>>>(X, Ws, bWs, a1, a2, ba, Tt, E1, E1s, E2, E2s, Xf);
    dim3 grid(NN / 32, nqb);
    mas_main4<<<grid, 256, 0, stream>>>(Xf, Tt, E1, E1s, E2, E2s, numpart, zpart, out, nqb);
    if (nqb > 1)
        mas_comb4<<<NN * DD / 256, 256, 0, stream>>>(numpart, zpart, out, nqb);
}

// Round 6
// 67.086 us; speedup vs baseline: 7.3603x; 1.3211x over previous
//
#include <hip/hip_runtime.h>

#define NN 8192
#define DD 64
#define NL 3
#define LOG2E 1.4426950408889634f

typedef _Float16 f16x8 __attribute__((ext_vector_type(8)));
typedef _Float16 f16x2 __attribute__((ext_vector_type(2)));
typedef float f32x2 __attribute__((ext_vector_type(2)));
typedef float f32x16 __attribute__((ext_vector_type(16)));

union F16U { f16x8 v8; f16x2 h2[4]; };

// Prep kernel.
// Blocks [0,96): per-row f1/f2 for 3 layers -> exp-domain tables:
//   a=(f1+ba)*log2e, b=f2*log2e
//   E1[l][i]=2^(a-4) f32, E1s[l][i]=2^(0.2a-4) f32   (2^-4 range scale; the
//     per-row scale cancels EXACTLY in sum(w x)/(Z0 Z1 Z2))
//   E2h[l][j]=2^b f16, E2sh[l][j]=2^(0.2b) f16
//   Identity: e_l = max(E1*E2h, E1s*E2sh)  (lrelu(c) vs 0.2c crosses at c=0,
//   exp monotone => select == max).
// Blocks [96,352): X (f32 row-major) -> fp16 in 32x32x16 B-fragment order.
__global__ __launch_bounds__(256) void mas_prep(const float* __restrict__ X,
                                                const float* __restrict__ Ws,
                                                const float* __restrict__ bWs,
                                                const float* __restrict__ a1,
                                                const float* __restrict__ a2,
                                                const float* __restrict__ ba,
                                                float* __restrict__ E1,
                                                float* __restrict__ E1s,
                                                _Float16* __restrict__ E2h,
                                                _Float16* __restrict__ E2sh,
                                                _Float16* __restrict__ Xf) {
    if (blockIdx.x < 96) {
        const int l = blockIdx.x >> 5;
        const int i = ((blockIdx.x & 31) << 8) + threadIdx.x;

        float xr[DD];
        const float4* X4 = (const float4*)(X + (size_t)i * DD);
#pragma unroll
        for (int q = 0; q < DD / 4; ++q) {
            float4 v = X4[q];
            xr[4 * q + 0] = v.x; xr[4 * q + 1] = v.y;
            xr[4 * q + 2] = v.z; xr[4 * q + 3] = v.w;
        }

        const float* W   = Ws  + l * DD * DD;
        const float* a1l = a1  + l * DD;
        const float* a2l = a2  + l * DD;
        const float* bwl = bWs + l * DD;

        float f1 = 0.f, f2 = 0.f;
#pragma unroll 4
        for (int d = 0; d < DD; ++d) {
            float wh = bwl[d];
            const float* wr = W + d * DD;
#pragma unroll
            for (int k = 0; k < DD; ++k) wh = fmaf(xr[k], wr[k], wh);
            f1 = fmaf(wh, a1l[d], f1);
            f2 = fmaf(wh, a2l[d], f2);
        }
        const float a = (f1 + ba[l]) * LOG2E;
        const float b = f2 * LOG2E;
        E1  [l * NN + i] = exp2f(a) * 0.0625f;
        E1s [l * NN + i] = exp2f(0.2f * a) * 0.0625f;
        E2h [l * NN + i] = (_Float16)exp2f(b);
        E2sh[l * NN + i] = (_Float16)exp2f(0.2f * b);
    } else {
        // X -> fp16 B-fragment order. Element (S,tile,lane,e) holds
        // X[S*16 + (lane>>5)*8 + e][tile*32 + (lane&31)]; flat = (S*2+tile)*64+lane.
        const int t = (blockIdx.x - 96) * 256 + threadIdx.x;   // 0..65535
        const int lane = t & 63;
        const int st = t >> 6;
        const int S = st >> 1, tl = st & 1;
        const int d = tl * 32 + (lane & 31);
        const int j0 = S * 16 + (lane >> 5) * 8;
        f16x8 v;
#pragma unroll
        for (int e = 0; e < 8; ++e) v[e] = (_Float16)X[(size_t)(j0 + e) * DD + d];
        *(f16x8*)(Xf + (size_t)t * 8) = v;
    }
}

// Main: wave = 32-row tile x j-span. All w-generation in packed f16
// (v_pk_mul/max/min), z via cvt+packed f32 adds. No LDS, no transcendentals,
// no compares in the loop.
__global__ __launch_bounds__(256, 4) void mas_main5(const _Float16* __restrict__ Xf,
                                                    const float* __restrict__ E1,
                                                    const float* __restrict__ E1s,
                                                    const _Float16* __restrict__ E2h,
                                                    const _Float16* __restrict__ E2sh,
                                                    float* __restrict__ numpart,
                                                    float* __restrict__ zpart,
                                                    float* __restrict__ out,
                                                    int nqb) {
    __shared__ float red[4][64][33];
    __shared__ float zred[4][3][32];
    __shared__ float zfin[3][32];

    const int tid  = threadIdx.x;
    const int lane = tid & 63;
    const int wv   = tid >> 6;
    const int hi   = lane >> 5;
    const int row  = lane & 31;
    const int rt   = blockIdx.x;
    const int q    = blockIdx.y;
    const int i    = rt * 32 + row;

    const float e10f = E1[0 * NN + i], e11f = E1[1 * NN + i], e12f = E1[2 * NN + i];
    const float f10f = E1s[0 * NN + i], f11f = E1s[1 * NN + i], f12f = E1s[2 * NN + i];
    const f16x2 E10p = {(_Float16)e10f, (_Float16)e10f};
    const f16x2 E11p = {(_Float16)e11f, (_Float16)e11f};
    const f16x2 E12p = {(_Float16)e12f, (_Float16)e12f};
    const f16x2 F10p = {(_Float16)f10f, (_Float16)f10f};
    const f16x2 F11p = {(_Float16)f11f, (_Float16)f11f};
    const f16x2 F12p = {(_Float16)f12f, (_Float16)f12f};
    const f16x2 clampP = {(_Float16)60000.0f, (_Float16)60000.0f};

    const int jspan = NN / nqb;
    const int wspan = jspan >> 2;
    const int jbase = q * jspan + wv * wspan;
    const int s0    = jbase >> 4;
    const int nst   = wspan >> 4;

    const _Float16* q20 = E2h  + 0 * NN + jbase + hi * 8;
    const _Float16* q21 = E2h  + 1 * NN + jbase + hi * 8;
    const _Float16* q22 = E2h  + 2 * NN + jbase + hi * 8;
    const _Float16* r20 = E2sh + 0 * NN + jbase + hi * 8;
    const _Float16* r21 = E2sh + 1 * NN + jbase + hi * 8;
    const _Float16* r22 = E2sh + 2 * NN + jbase + hi * 8;
    const f16x8* pB = (const f16x8*)Xf + (size_t)s0 * 128 + lane;

    f32x16 acc0 = {};
    f32x16 acc1 = {};
    f32x2 z0p = {0.f, 0.f}, z1p = {0.f, 0.f}, z2p = {0.f, 0.f};

    for (int s = 0; s < nst; ++s) {
        const int o = s * 16;
        F16U g0, g1, g2, h0, h1, h2v;
        g0.v8  = *(const f16x8*)(q20 + o);
        g1.v8  = *(const f16x8*)(q21 + o);
        g2.v8  = *(const f16x8*)(q22 + o);
        h0.v8  = *(const f16x8*)(r20 + o);
        h1.v8  = *(const f16x8*)(r21 + o);
        h2v.v8 = *(const f16x8*)(r22 + o);
        const f16x8 vb0 = pB[s * 128];
        const f16x8 vb1 = pB[s * 128 + 64];

        F16U wa;
#pragma unroll
        for (int g = 0; g < 4; ++g) {
            const f16x2 e0 = __builtin_elementwise_max(E10p * g0.h2[g], F10p * h0.h2[g]);
            const f16x2 e1 = __builtin_elementwise_max(E11p * g1.h2[g], F11p * h1.h2[g]);
            const f16x2 e2 = __builtin_elementwise_max(E12p * g2.h2[g], F12p * h2v.h2[g]);
            z0p += (f32x2){(float)e0[0], (float)e0[1]};
            z1p += (f32x2){(float)e1[0], (float)e1[1]};
            z2p += (f32x2){(float)e2[0], (float)e2[1]};
            wa.h2[g] = __builtin_elementwise_min(e0 * e1 * e2, clampP);
        }
        acc0 = __builtin_amdgcn_mfma_f32_32x32x16_f16(wa.v8, vb0, acc0, 0, 0, 0);
        acc1 = __builtin_amdgcn_mfma_f32_32x32x16_f16(wa.v8, vb1, acc1, 0, 0, 0);
    }

    float z0 = z0p[0] + z0p[1];
    float z1 = z1p[0] + z1p[1];
    float z2 = z2p[0] + z2p[1];
    // lanes (l, l+32) hold same row, disjoint j-halves
    z0 += __shfl_xor(z0, 32);
    z1 += __shfl_xor(z1, 32);
    z2 += __shfl_xor(z2, 32);

    // C frags -> LDS: C row = (reg&3) + 8*(reg>>2) + 4*hi, col = lane&31 (+32)
#pragma unroll
    for (int g = 0; g < 4; ++g) {
        const int rb = 8 * g + 4 * hi;
        *(float4*)&red[wv][row][rb] =
            make_float4(acc0[4 * g], acc0[4 * g + 1], acc0[4 * g + 2], acc0[4 * g + 3]);
        *(float4*)&red[wv][row + 32][rb] =
            make_float4(acc1[4 * g], acc1[4 * g + 1], acc1[4 * g + 2], acc1[4 * g + 3]);
    }
    if (lane < 32) {
        zred[wv][0][row] = z0; zred[wv][1][row] = z1; zred[wv][2][row] = z2;
    }
    __syncthreads();

    if (tid < 96) {
        const int l = tid >> 5, r = tid & 31;
        const float Z = zred[0][l][r] + zred[1][l][r] + zred[2][l][r] + zred[3][l][r];
        if (nqb > 1) zpart[((size_t)q * 3 + l) * NN + rt * 32 + r] = Z;
        else zfin[l][r] = Z;
    }
    __syncthreads();

    {
        const int col = tid & 63;
        const int r0 = (tid >> 6) * 8;
        float s[8] = {0, 0, 0, 0, 0, 0, 0, 0};
#pragma unroll
        for (int w = 0; w < 4; ++w) {
            const float4 u = *(const float4*)&red[w][col][r0];
            const float4 v = *(const float4*)&red[w][col][r0 + 4];
            s[0] += u.x; s[1] += u.y; s[2] += u.z; s[3] += u.w;
            s[4] += v.x; s[5] += v.y; s[6] += v.z; s[7] += v.w;
        }
        if (nqb > 1) {
            float* np = numpart + ((size_t)q * NN + (size_t)rt * 32) * DD;
#pragma unroll
            for (int u2 = 0; u2 < 8; ++u2) np[(size_t)(r0 + u2) * DD + col] = s[u2];
        } else {
#pragma unroll
            for (int u2 = 0; u2 < 8; ++u2) {
                const int r = r0 + u2;
                const float inv = 1.0f / (zfin[0][r] * (zfin[1][r] * zfin[2][r]));
                out[(size_t)(rt * 32 + r) * DD + col] = s[u2] * inv;
            }
        }
    }
}

// Combine j-split partials (fixed order, deterministic). Scales cancel.
__global__ __launch_bounds__(256) void mas_comb5(const float* __restrict__ numpart,
                                                 const float* __restrict__ zpart,
                                                 float* __restrict__ out, int nqb) {
    const int idx = blockIdx.x * 256 + threadIdx.x;
    const int i = idx >> 6;
    float s = 0.f;
    for (int q = 0; q < nqb; ++q) s += numpart[(size_t)q * NN * DD + idx];
    float Z0 = 0.f, Z1 = 0.f, Z2 = 0.f;
    for (int q = 0; q < nqb; ++q) {
        Z0 += zpart[((size_t)q * 3 + 0) * NN + i];
        Z1 += zpart[((size_t)q * 3 + 1) * NN + i];
        Z2 += zpart[((size_t)q * 3 + 2) * NN + i];
    }
    out[idx] = s / (Z0 * (Z1 * Z2));
}

extern "C" void kernel_launch(void* const* d_in, const int* in_sizes, int n_in,
                              void* d_out, int out_size, void* d_ws, size_t ws_size,
                              hipStream_t stream) {
    const float* X   = (const float*)d_in[0];
    // d_in[1] = A : unused by the reference computation (shape only)
    const float* Ws  = (const float*)d_in[2];
    const float* bWs = (const float*)d_in[3];
    const float* a1  = (const float*)d_in[4];
    const float* a2  = (const float*)d_in[5];
    const float* ba  = (const float*)d_in[6];
    float* out = (float*)d_out;

    float* E1  = (float*)d_ws;                   // [3][NN] f32
    float* E1s = E1 + NL * NN;                   // [3][NN] f32
    _Float16* E2h  = (_Float16*)(E1s + NL * NN); // [3][NN] f16
    _Float16* E2sh = E2h + NL * NN;              // [3][NN] f16
    _Float16* Xf   = E2sh + NL * NN;             // [NN*DD] f16 fragment order

    const size_t fixed = (size_t)(2 * NL * NN) * 4 + (size_t)(2 * NL * NN) * 2
                       + (size_t)NN * DD * 2;
    const size_t per_q = (size_t)NN * DD * 4 + (size_t)NL * NN * 4;
    int nqb = 1;
    if (ws_size >= fixed + 4 * per_q) nqb = 4;
    else if (ws_size >= fixed + 2 * per_q) nqb = 2;

    float* numpart = (float*)(Xf + (size_t)NN * DD);  // [nqb][NN][DD]
    float* zpart   = numpart + (size_t)nqb * NN * DD; // [nqb][3][NN]

    mas_prep<<<352, 256, 0, stream>>>(X, Ws, bWs, a1, a2, ba, E1, E1s, E2h, E2sh, Xf);
    dim3 grid(NN / 32, nqb);
    mas_main5<<<grid, 256, 0, stream>>>(Xf, E1, E1s, E2h, E2sh, numpart, zpart, out, nqb);
    if (nqb > 1)
        mas_comb5<<<NN * DD / 256, 256, 0, stream>>>(numpart, zpart, out, nqb);
}